// Round 33
// baseline (151.817 us; speedup 1.0000x reference)
//
#include <hip/hip_runtime.h>
#include <math.h>

#define ALPHA 0.2f
#define BKT 128      // rows per bucket
#define CAP 4608     // padded bucket capacity (mean 4096 + 8 sigma)
#define PCHUNK 4096  // edges per binA block
#define WT_PITCH 264 // ushorts per sW row (256 + 8 pad; spreads banks)

using f32x4 = __attribute__((ext_vector_type(4))) float;
using s16x8 = __attribute__((ext_vector_type(8))) short;

__device__ __forceinline__ unsigned short f2bf(float x) {
  unsigned u = __float_as_uint(x);
  unsigned r = (u + 0x7FFFu + ((u >> 16) & 1u)) >> 16;
  return (unsigned short)r;
}
__device__ __forceinline__ float bflo(unsigned s) { return __uint_as_float(s << 16); }
__device__ __forceinline__ float bfhi(unsigned s) { return __uint_as_float(s & 0xFFFF0000u); }
__device__ __forceinline__ unsigned fkey(float x) {
  unsigned b = __float_as_uint(x);
  return (b & 0x80000000u) ? ~b : (b | 0x80000000u);
}
__device__ __forceinline__ float kinv(unsigned k) {
  unsigned b = (k & 0x80000000u) ? (k & 0x7FFFFFFFu) : ~k;
  return __uint_as_float(b);
}

// ---------------- setup: W -> bf16 W^T (64KB) + padded-bucket tail init ----------------
__global__ __launch_bounds__(256) void wcvt(const float* __restrict__ W,
                                            unsigned short* __restrict__ WtG,
                                            unsigned* __restrict__ tail, int NBKT) {
  int g = blockIdx.x * 256 + threadIdx.x;
  if (g < NBKT) tail[g] = (unsigned)(g * CAP);
  int c = threadIdx.x & 127;
  int k0 = blockIdx.x * 64 + (threadIdx.x >> 7) * 32;
  for (int k = k0; k < k0 + 32; k += 2) {
    unsigned short b0 = f2bf(W[(size_t)k * 128 + c]);
    unsigned short b1 = f2bf(W[(size_t)(k + 1) * 128 + c]);
    *reinterpret_cast<ushort2*>(&WtG[(size_t)c * 256 + k]) = make_ushort2(b0, b1);
  }
}

// ---------------- MFMA bf16 GEMM: 128-row blocks, LDS-staged W^T, unrolled ks ----------------
__global__ __launch_bounds__(256) void gemm_fused(
    const float* __restrict__ seq, const unsigned short* __restrict__ WtG,
    const float* __restrict__ a1w, const float* __restrict__ a1b,
    const float* __restrict__ a2w, const float* __restrict__ a2b,
    unsigned* __restrict__ hb, float* __restrict__ f1, float* __restrict__ f2, int N) {
  __shared__ unsigned short sW[128][WT_PITCH];  // 67.6 KB
  const int tid = threadIdx.x;
  const int lane = tid & 63;
  const int wv = tid >> 6;    // wave 0..3
  const int lr = lane & 15;   // fragment row/col index
  const int lq = lane >> 4;   // k-group 0..3
  const int rowbase = blockIdx.x * 128;

  // stage WtG -> sW: 128 rows x 32 uint4 segs (8 ushorts each) = 4096, 16/thread
  #pragma unroll
  for (int l = 0; l < 16; ++l) {
    int i = tid + l * 256;
    int c = i >> 5, seg = i & 31;
    *reinterpret_cast<uint4*>(&sW[c][seg * 8]) =
        *reinterpret_cast<const uint4*>(WtG + (size_t)c * 256 + seg * 8);
  }
  __syncthreads();

  int r0 = rowbase + wv * 32 + lr;
  int r1 = r0 + 16;
  int gr0 = (r0 < N - 1) ? r0 : (N - 1);
  int gr1 = (r1 < N - 1) ? r1 : (N - 1);
  const float* arow0 = seq + (size_t)gr0 * 256 + lq * 8;
  const float* arow1 = seq + (size_t)gr1 * 256 + lq * 8;
  const unsigned short* wbase = &sW[lr][lq * 8];

  f32x4 acc[2][8] = {};

  #pragma unroll
  for (int ks = 0; ks < 8; ++ks) {
    s16x8 b[8];
    #pragma unroll
    for (int nf = 0; nf < 8; ++nf) {
      b[nf] = *reinterpret_cast<const s16x8*>(wbase + (size_t)nf * 16 * WT_PITCH + ks * 32);
    }
    float4 p00 = *reinterpret_cast<const float4*>(arow0 + ks * 32);
    float4 p01 = *reinterpret_cast<const float4*>(arow0 + ks * 32 + 4);
    float4 p10 = *reinterpret_cast<const float4*>(arow1 + ks * 32);
    float4 p11 = *reinterpret_cast<const float4*>(arow1 + ks * 32 + 4);

    s16x8 a0, a1;
    a0[0] = (short)f2bf(p00.x); a0[1] = (short)f2bf(p00.y);
    a0[2] = (short)f2bf(p00.z); a0[3] = (short)f2bf(p00.w);
    a0[4] = (short)f2bf(p01.x); a0[5] = (short)f2bf(p01.y);
    a0[6] = (short)f2bf(p01.z); a0[7] = (short)f2bf(p01.w);
    a1[0] = (short)f2bf(p10.x); a1[1] = (short)f2bf(p10.y);
    a1[2] = (short)f2bf(p10.z); a1[3] = (short)f2bf(p10.w);
    a1[4] = (short)f2bf(p11.x); a1[5] = (short)f2bf(p11.y);
    a1[6] = (short)f2bf(p11.z); a1[7] = (short)f2bf(p11.w);

    #pragma unroll
    for (int nf = 0; nf < 8; ++nf) {
      acc[0][nf] = __builtin_amdgcn_mfma_f32_16x16x32_bf16(a0, b[nf], acc[0][nf], 0, 0, 0);
      acc[1][nf] = __builtin_amdgcn_mfma_f32_16x16x32_bf16(a1, b[nf], acc[1][nf], 0, 0, 0);
    }
  }

  float w1[8], w2[8];
  #pragma unroll
  for (int nf = 0; nf < 8; ++nf) { w1[nf] = a1w[nf * 16 + lr]; w2[nf] = a2w[nf * 16 + lr]; }
  float b1s = a1b[0], b2s = a2b[0];

  #pragma unroll
  for (int mf = 0; mf < 2; ++mf) {
    #pragma unroll
    for (int reg = 0; reg < 4; ++reg) {
      int gr = rowbase + wv * 32 + mf * 16 + lq * 4 + reg;
      float hv[8];
      float p1 = 0.0f, p2 = 0.0f;
      #pragma unroll
      for (int nf = 0; nf < 8; ++nf) {
        hv[nf] = acc[mf][nf][reg];
        p1 += hv[nf] * w1[nf];
        p2 += hv[nf] * w2[nf];
      }
      #pragma unroll
      for (int off = 1; off <= 8; off <<= 1) {
        p1 += __shfl_xor(p1, off);
        p2 += __shfl_xor(p2, off);
      }
      bool rowok = gr < N;
      #pragma unroll
      for (int nf = 0; nf < 8; ++nf) {
        int mine = (int)f2bf(hv[nf]);
        int oth = __shfl_xor(mine, 1);
        if (rowok && !(lr & 1)) {
          unsigned packed = (unsigned)mine | ((unsigned)oth << 16);
          hb[(size_t)gr * 64 + nf * 8 + (lr >> 1)] = packed;
        }
      }
      if (rowok && lr == 0) { f1[gr] = p1 + b1s; f2[gr] = p2 + b2s; }
    }
  }
}

// ---------------- Pass A: LDS radix binning into padded row-buckets ----------------
__global__ __launch_bounds__(256) void binA(const int* __restrict__ row,
                                            const int* __restrict__ col,
                                            const float* __restrict__ w,
                                            const float* __restrict__ f1,
                                            const float* __restrict__ f2,
                                            unsigned* __restrict__ tail,
                                            uint2* __restrict__ stg, int E, int NBKT) {
  __shared__ unsigned bcnt[512];
  __shared__ unsigned bcur[512];
  __shared__ uint2 sstg[PCHUNK];
  const int tid = threadIdx.x;
  const int lane = tid & 63, wv = tid >> 6;
  const int base = blockIdx.x * PCHUNK;

  for (int i = tid; i < 512; i += 256) bcnt[i] = 0u;
  __syncthreads();

  float vv[16];
  unsigned pk[16];
  if (base + PCHUNK <= E) {
    #pragma unroll
    for (int g = 0; g < 4; ++g) {
      int idx = base + g * 1024 + tid * 4;
      int4 r4 = *reinterpret_cast<const int4*>(row + idx);
      int4 c4 = *reinterpret_cast<const int4*>(col + idx);
      float4 w4 = *reinterpret_cast<const float4*>(w + idx);
      int rr[4] = {r4.x, r4.y, r4.z, r4.w};
      int cc[4] = {c4.x, c4.y, c4.z, c4.w};
      float ww[4] = {w4.x, w4.y, w4.z, w4.w};
      #pragma unroll
      for (int i = 0; i < 4; ++i) {
        int l = g * 4 + i;
        float x = f1[rr[i]] + f2[cc[i]];
        x = x > 0.0f ? x : ALPHA * x;
        x *= ww[i];
        vv[l] = x;
        pk[l] = ((unsigned)cc[i] << 16) | (unsigned)rr[i];
        atomicAdd(&bcnt[rr[i] >> 7], 1u);
      }
    }
  } else {
    #pragma unroll
    for (int l = 0; l < 16; ++l) {
      int idx = base + tid + l * 256;
      if (idx < E) {
        int r = row[idx], c = col[idx];
        float x = f1[r] + f2[c];
        x = x > 0.0f ? x : ALPHA * x;
        x *= w[idx];
        vv[l] = x;
        pk[l] = ((unsigned)c << 16) | (unsigned)r;
        atomicAdd(&bcnt[r >> 7], 1u);
      } else {
        pk[l] = 0xFFFFFFFFu;
      }
    }
  }
  __syncthreads();

  unsigned a0 = bcnt[2 * tid], a1 = bcnt[2 * tid + 1];
  unsigned pairv = a0 + a1;
  unsigned x = pairv;
  #pragma unroll
  for (int d = 1; d < 64; d <<= 1) {
    unsigned y = __shfl_up(x, d);
    if (lane >= d) x += y;
  }
  __shared__ unsigned wsum[4];
  if (lane == 63) wsum[wv] = x;
  __syncthreads();
  unsigned woff = 0;
  for (int i = 0; i < wv; ++i) woff += wsum[i];
  unsigned exclp = x + woff - pairv;
  bcur[2 * tid] = exclp;
  bcur[2 * tid + 1] = exclp + a0;
  __syncthreads();

  if (base + PCHUNK <= E) {
    #pragma unroll
    for (int l = 0; l < 16; ++l) {
      unsigned b = (pk[l] & 0xFFFFu) >> 7;
      unsigned p = atomicAdd(&bcur[b], 1u);
      sstg[p] = make_uint2(__float_as_uint(vv[l]), pk[l]);
    }
  } else {
    #pragma unroll
    for (int l = 0; l < 16; ++l) {
      if (pk[l] != 0xFFFFFFFFu) {
        unsigned b = (pk[l] & 0xFFFFu) >> 7;
        unsigned p = atomicAdd(&bcur[b], 1u);
        sstg[p] = make_uint2(__float_as_uint(vv[l]), pk[l]);
      }
    }
  }
  __syncthreads();

  for (int b = tid; b < NBKT; b += 256) {
    unsigned c = bcnt[b];
    if (c) {
      unsigned g = atomicAdd(&tail[b], c);
      bcnt[b] = g - (bcur[b] - c);  // delta = globalstart - ldsstart
    }
  }
  __syncthreads();

  int ne = E - base; if (ne > PCHUNK) ne = PCHUNK;
  for (int i = tid; i < ne; i += 256) {
    uint2 e2 = sstg[i];
    unsigned b = (e2.y & 0xFFFFu) >> 7;
    __builtin_nontemporal_store(e2.x, &stg[i + bcnt[b]].x);
    __builtin_nontemporal_store(e2.y, &stg[i + bcnt[b]].y);
  }
}

// ---------------- Pass B: rowse + softmax + CSR place (eb packed to 4B/edge) ----------------
__global__ __launch_bounds__(256) void binB(const unsigned* __restrict__ tail,
                                            const uint2* __restrict__ stg,
                                            unsigned* __restrict__ eb,
                                            uint2* __restrict__ rowse,
                                            float* __restrict__ rdArr, int N) {
  const int b = blockIdx.x;
  const int r0 = b * BKT;
  int r1 = r0 + BKT; if (r1 > N) r1 = N;
  const int nrows = r1 - r0;
  __shared__ unsigned cnt[BKT];
  __shared__ unsigned cur[BKT];
  __shared__ unsigned mkey[BKT];
  __shared__ float dsum[BKT];
  const int tid = threadIdx.x;
  if (tid < BKT) { cnt[tid] = 0u; mkey[tid] = 0u; dsum[tid] = 0.0f; }
  __syncthreads();
  const int sA = b * CAP, eA = (int)tail[b];

  for (int i = sA + tid; i < eA; i += 256) {
    uint2 e2 = stg[i];
    unsigned rl = e2.y & 127u;
    atomicAdd(&cnt[rl], 1u);
    atomicMax(&mkey[rl], fkey(__uint_as_float(e2.x)));
  }
  __syncthreads();

  unsigned orig = (tid < BKT) ? cnt[tid] : 0u;
  for (int off = 1; off < BKT; off <<= 1) {
    unsigned v = 0u;
    if (tid < BKT && tid >= off) v = cnt[tid - off];
    __syncthreads();
    if (tid < BKT) cnt[tid] += v;
    __syncthreads();
  }
  if (tid < nrows) {
    unsigned start = (unsigned)sA + cnt[tid] - orig;  // exclusive
    cur[tid] = start;
    rowse[r0 + tid] = make_uint2(start, start + orig);
  }
  __syncthreads();

  for (int i = sA + tid; i < eA; i += 256) {
    uint2 e2 = stg[i];
    unsigned rl = e2.y & 127u;
    unsigned c = e2.y >> 16;
    float ex = __expf(__uint_as_float(e2.x) - kinv(mkey[rl]));
    atomicAdd(&dsum[rl], ex);
    unsigned slot = atomicAdd(&cur[rl], 1u);
    __builtin_nontemporal_store(((unsigned)f2bf(ex) << 16) | c, &eb[slot]);
  }
  __syncthreads();

  if (tid < nrows) rdArr[r0 + tid] = 1.0f / fmaxf(dsum[tid], 1e-38f);
}

// ---------------- pull SpMM (gather-only; 4B eb; 16/8-wide tiers + tail) ----------------
__global__ __launch_bounds__(256) void spmm(const uint2* __restrict__ rowse,
                                            const float* __restrict__ rdArr,
                                            const unsigned* __restrict__ eb,
                                            const unsigned* __restrict__ hb,
                                            const float* __restrict__ bias,
                                            float* __restrict__ out, int N) {
  int wid = (blockIdx.x * 256 + threadIdx.x) >> 6;
  int lane = threadIdx.x & 63;
  if (wid >= N) return;
  const uint2 se = rowse[wid];
  const int s = (int)se.x, e = (int)se.y;
  const int qw = lane >> 4;
  const int ql = lane & 15;
  const float rd = rdArr[wid];

  float acc[8] = {};
  int j0 = s + lane;
  float cf_reg = 0.0f;
  int c_reg = 0;
  if (j0 < e) {
    unsigned t = __builtin_nontemporal_load(&eb[j0]);
    cf_reg = bfhi(t) * rd;
    c_reg = (int)(t & 0xFFFFu);
  }
  for (int base = s; base < e; base += 64) {
    if (base != s) {
      int j = base + lane;
      if (j < e) {
        unsigned t = __builtin_nontemporal_load(&eb[j]);
        cf_reg = bfhi(t) * rd;
        c_reg = (int)(t & 0xFFFFu);
      } else {
        cf_reg = 0.0f; c_reg = 0;
      }
    }
    int nloc = e - base; if (nloc > 64) nloc = 64;
    const int full16 = nloc & ~15;
    int bk = 0;
    for (; bk < full16; bk += 16) {
      float cf0 = __shfl(cf_reg, bk + qw);
      int   cc0 = __shfl(c_reg,  bk + qw);
      float cf1 = __shfl(cf_reg, bk + 4 + qw);
      int   cc1 = __shfl(c_reg,  bk + 4 + qw);
      float cf2 = __shfl(cf_reg, bk + 8 + qw);
      int   cc2 = __shfl(c_reg,  bk + 8 + qw);
      float cf3 = __shfl(cf_reg, bk + 12 + qw);
      int   cc3 = __shfl(c_reg,  bk + 12 + qw);
      const uint4 g0 = *reinterpret_cast<const uint4*>(hb + (size_t)cc0 * 64 + ql * 4);
      const uint4 g1 = *reinterpret_cast<const uint4*>(hb + (size_t)cc1 * 64 + ql * 4);
      const uint4 g2 = *reinterpret_cast<const uint4*>(hb + (size_t)cc2 * 64 + ql * 4);
      const uint4 g3 = *reinterpret_cast<const uint4*>(hb + (size_t)cc3 * 64 + ql * 4);
      acc[0] += cf0 * bflo(g0.x); acc[1] += cf0 * bfhi(g0.x);
      acc[2] += cf0 * bflo(g0.y); acc[3] += cf0 * bfhi(g0.y);
      acc[4] += cf0 * bflo(g0.z); acc[5] += cf0 * bfhi(g0.z);
      acc[6] += cf0 * bflo(g0.w); acc[7] += cf0 * bfhi(g0.w);
      acc[0] += cf1 * bflo(g1.x); acc[1] += cf1 * bfhi(g1.x);
      acc[2] += cf1 * bflo(g1.y); acc[3] += cf1 * bfhi(g1.y);
      acc[4] += cf1 * bflo(g1.z); acc[5] += cf1 * bfhi(g1.z);
      acc[6] += cf1 * bflo(g1.w); acc[7] += cf1 * bfhi(g1.w);
      acc[0] += cf2 * bflo(g2.x); acc[1] += cf2 * bfhi(g2.x);
      acc[2] += cf2 * bflo(g2.y); acc[3] += cf2 * bfhi(g2.y);
      acc[4] += cf2 * bflo(g2.z); acc[5] += cf2 * bfhi(g2.z);
      acc[6] += cf2 * bflo(g2.w); acc[7] += cf2 * bfhi(g2.w);
      acc[0] += cf3 * bflo(g3.x); acc[1] += cf3 * bfhi(g3.x);
      acc[2] += cf3 * bflo(g3.y); acc[3] += cf3 * bfhi(g3.y);
      acc[4] += cf3 * bflo(g3.z); acc[5] += cf3 * bfhi(g3.z);
      acc[6] += cf3 * bflo(g3.w); acc[7] += cf3 * bfhi(g3.w);
    }
    const int full8 = nloc & ~7;
    for (; bk < full8; bk += 8) {  // 2 unconditional sub-steps
      float cf0 = __shfl(cf_reg, bk + qw);
      int   cc0 = __shfl(c_reg,  bk + qw);
      float cf1 = __shfl(cf_reg, bk + 4 + qw);
      int   cc1 = __shfl(c_reg,  bk + 4 + qw);
      const uint4 g0 = *reinterpret_cast<const uint4*>(hb + (size_t)cc0 * 64 + ql * 4);
      const uint4 g1 = *reinterpret_cast<const uint4*>(hb + (size_t)cc1 * 64 + ql * 4);
      acc[0] += cf0 * bflo(g0.x); acc[1] += cf0 * bfhi(g0.x);
      acc[2] += cf0 * bflo(g0.y); acc[3] += cf0 * bfhi(g0.y);
      acc[4] += cf0 * bflo(g0.z); acc[5] += cf0 * bfhi(g0.z);
      acc[6] += cf0 * bflo(g0.w); acc[7] += cf0 * bfhi(g0.w);
      acc[0] += cf1 * bflo(g1.x); acc[1] += cf1 * bfhi(g1.x);
      acc[2] += cf1 * bflo(g1.y); acc[3] += cf1 * bfhi(g1.y);
      acc[4] += cf1 * bflo(g1.z); acc[5] += cf1 * bfhi(g1.z);
      acc[6] += cf1 * bflo(g1.w); acc[7] += cf1 * bfhi(g1.w);
    }
    for (; bk < nloc; bk += 4) {  // tail: <=1 predicated sub-step
      int k = bk + qw;
      int ksrc = (k < 64) ? k : 0;
      float cfk = __shfl(cf_reg, ksrc);
      int ck = __shfl(c_reg, ksrc);
      if (k < nloc) {
        const uint4 hv = *reinterpret_cast<const uint4*>(hb + (size_t)ck * 64 + ql * 4);
        acc[0] += cfk * bflo(hv.x); acc[1] += cfk * bfhi(hv.x);
        acc[2] += cfk * bflo(hv.y); acc[3] += cfk * bfhi(hv.y);
        acc[4] += cfk * bflo(hv.z); acc[5] += cfk * bfhi(hv.z);
        acc[6] += cfk * bflo(hv.w); acc[7] += cfk * bfhi(hv.w);
      }
    }
  }

  #pragma unroll
  for (int i = 0; i < 8; ++i) {
    acc[i] += __shfl_xor(acc[i], 16);
    acc[i] += __shfl_xor(acc[i], 32);
  }

  if (qw == 0) {
    const int d0 = ql * 8;
    float4 b0 = *reinterpret_cast<const float4*>(bias + d0);
    float4 b1 = *reinterpret_cast<const float4*>(bias + d0 + 4);
    float* op = out + (size_t)wid * 128 + d0;
    __builtin_nontemporal_store(fmaxf(acc[0] + b0.x, 0.0f), op + 0);
    __builtin_nontemporal_store(fmaxf(acc[1] + b0.y, 0.0f), op + 1);
    __builtin_nontemporal_store(fmaxf(acc[2] + b0.z, 0.0f), op + 2);
    __builtin_nontemporal_store(fmaxf(acc[3] + b0.w, 0.0f), op + 3);
    __builtin_nontemporal_store(fmaxf(acc[4] + b1.x, 0.0f), op + 4);
    __builtin_nontemporal_store(fmaxf(acc[5] + b1.y, 0.0f), op + 5);
    __builtin_nontemporal_store(fmaxf(acc[6] + b1.z, 0.0f), op + 6);
    __builtin_nontemporal_store(fmaxf(acc[7] + b1.w, 0.0f), op + 7);
  }
}

extern "C" void kernel_launch(void* const* d_in, const int* in_sizes, int n_in,
                              void* d_out, int out_size, void* d_ws, size_t ws_size,
                              hipStream_t stream) {
  const float* seq    = (const float*)d_in[0];
  const int*   erow   = (const int*)d_in[1];
  const int*   ecol   = (const int*)d_in[2];
  const float* weight = (const float*)d_in[3];
  const float* W      = (const float*)d_in[4];
  const float* a1w    = (const float*)d_in[5];
  const float* a1b    = (const float*)d_in[6];
  const float* a2w    = (const float*)d_in[7];
  const float* a2b    = (const float*)d_in[8];
  const float* bias   = (const float*)d_in[9];
  const int N = in_sizes[0] / 256;
  const int E = in_sizes[1];
  float* out = (float*)d_out;

  char* p = (char*)d_ws;
  auto alloc = [&](size_t bytes) -> char* {
    char* q = p;
    p += (bytes + 255) & ~(size_t)255;
    return q;
  };
  const int NBKT = (N + BKT - 1) / BKT;
  unsigned* hb       = (unsigned*)alloc((size_t)N * 64 * 4);
  float*    f1       = (float*)alloc((size_t)N * 4);
  float*    f2       = (float*)alloc((size_t)N * 4);
  uint2*    rowse    = (uint2*)alloc((size_t)N * 8);
  float*    rdArr    = (float*)alloc((size_t)N * 4);
  unsigned short* WtG = (unsigned short*)alloc((size_t)128 * 256 * 2);
  unsigned* tail     = (unsigned*)alloc((size_t)NBKT * 4);
  uint2*    stg      = (uint2*)alloc((size_t)NBKT * CAP * 8);
  unsigned* eb       = (unsigned*)alloc((size_t)NBKT * CAP * 4);

  wcvt<<<4, 256, 0, stream>>>(W, WtG, tail, NBKT);
  gemm_fused<<<(N + 127) / 128, 256, 0, stream>>>(seq, WtG, a1w, a1b, a2w, a2b, hb, f1, f2, N);
  binA<<<(E + PCHUNK - 1) / PCHUNK, 256, 0, stream>>>(erow, ecol, weight, f1, f2, tail, stg, E, NBKT);
  binB<<<NBKT, 256, 0, stream>>>(tail, stg, eb, rowse, rdArr, N);
  spmm<<<(N * 64 + 255) / 256, 256, 0, stream>>>(rowse, rdArr, eb, hb, bias, out, N);
}

// Round 34
// 121.970 us; speedup vs baseline: 1.2447x; 1.2447x over previous
//
#include <hip/hip_runtime.h>
#include <math.h>

#define ALPHA 0.2f
#define BKT 128      // rows per bucket
#define CAP 4608     // padded bucket capacity (mean 4096 + 8 sigma)
#define PCHUNK 4096  // edges per binA block
#define WT_PITCH 264 // ushorts per sW row (256 + 8 pad; spreads banks)

using f32x4 = __attribute__((ext_vector_type(4))) float;
using s16x8 = __attribute__((ext_vector_type(8))) short;

__device__ __forceinline__ unsigned short f2bf(float x) {
  unsigned u = __float_as_uint(x);
  unsigned r = (u + 0x7FFFu + ((u >> 16) & 1u)) >> 16;
  return (unsigned short)r;
}
__device__ __forceinline__ float bflo(unsigned s) { return __uint_as_float(s << 16); }
__device__ __forceinline__ float bfhi(unsigned s) { return __uint_as_float(s & 0xFFFF0000u); }
__device__ __forceinline__ unsigned fkey(float x) {
  unsigned b = __float_as_uint(x);
  return (b & 0x80000000u) ? ~b : (b | 0x80000000u);
}
__device__ __forceinline__ float kinv(unsigned k) {
  unsigned b = (k & 0x80000000u) ? (k & 0x7FFFFFFFu) : ~k;
  return __uint_as_float(b);
}

// ---------------- setup: W -> bf16 W^T (64KB) + padded-bucket tail init ----------------
__global__ __launch_bounds__(256) void wcvt(const float* __restrict__ W,
                                            unsigned short* __restrict__ WtG,
                                            unsigned* __restrict__ tail, int NBKT) {
  int g = blockIdx.x * 256 + threadIdx.x;
  if (g < NBKT) tail[g] = (unsigned)(g * CAP);
  int c = threadIdx.x & 127;
  int k0 = blockIdx.x * 64 + (threadIdx.x >> 7) * 32;
  for (int k = k0; k < k0 + 32; k += 2) {
    unsigned short b0 = f2bf(W[(size_t)k * 128 + c]);
    unsigned short b1 = f2bf(W[(size_t)(k + 1) * 128 + c]);
    *reinterpret_cast<ushort2*>(&WtG[(size_t)c * 256 + k]) = make_ushort2(b0, b1);
  }
}

// ---------------- MFMA bf16 GEMM: 128-row blocks, LDS-staged W^T, unrolled ks ----------------
__global__ __launch_bounds__(256) void gemm_fused(
    const float* __restrict__ seq, const unsigned short* __restrict__ WtG,
    const float* __restrict__ a1w, const float* __restrict__ a1b,
    const float* __restrict__ a2w, const float* __restrict__ a2b,
    unsigned* __restrict__ hb, float* __restrict__ f1, float* __restrict__ f2, int N) {
  __shared__ unsigned short sW[128][WT_PITCH];  // 67.6 KB
  const int tid = threadIdx.x;
  const int lane = tid & 63;
  const int wv = tid >> 6;    // wave 0..3
  const int lr = lane & 15;   // fragment row/col index
  const int lq = lane >> 4;   // k-group 0..3
  const int rowbase = blockIdx.x * 128;

  // stage WtG -> sW: 128 rows x 32 uint4 segs (8 ushorts each) = 4096, 16/thread
  #pragma unroll
  for (int l = 0; l < 16; ++l) {
    int i = tid + l * 256;
    int c = i >> 5, seg = i & 31;
    *reinterpret_cast<uint4*>(&sW[c][seg * 8]) =
        *reinterpret_cast<const uint4*>(WtG + (size_t)c * 256 + seg * 8);
  }
  __syncthreads();

  int r0 = rowbase + wv * 32 + lr;
  int r1 = r0 + 16;
  int gr0 = (r0 < N - 1) ? r0 : (N - 1);
  int gr1 = (r1 < N - 1) ? r1 : (N - 1);
  const float* arow0 = seq + (size_t)gr0 * 256 + lq * 8;
  const float* arow1 = seq + (size_t)gr1 * 256 + lq * 8;
  const unsigned short* wbase = &sW[lr][lq * 8];

  f32x4 acc[2][8] = {};

  #pragma unroll
  for (int ks = 0; ks < 8; ++ks) {
    s16x8 b[8];
    #pragma unroll
    for (int nf = 0; nf < 8; ++nf) {
      b[nf] = *reinterpret_cast<const s16x8*>(wbase + (size_t)nf * 16 * WT_PITCH + ks * 32);
    }
    float4 p00 = *reinterpret_cast<const float4*>(arow0 + ks * 32);
    float4 p01 = *reinterpret_cast<const float4*>(arow0 + ks * 32 + 4);
    float4 p10 = *reinterpret_cast<const float4*>(arow1 + ks * 32);
    float4 p11 = *reinterpret_cast<const float4*>(arow1 + ks * 32 + 4);

    s16x8 a0, a1;
    a0[0] = (short)f2bf(p00.x); a0[1] = (short)f2bf(p00.y);
    a0[2] = (short)f2bf(p00.z); a0[3] = (short)f2bf(p00.w);
    a0[4] = (short)f2bf(p01.x); a0[5] = (short)f2bf(p01.y);
    a0[6] = (short)f2bf(p01.z); a0[7] = (short)f2bf(p01.w);
    a1[0] = (short)f2bf(p10.x); a1[1] = (short)f2bf(p10.y);
    a1[2] = (short)f2bf(p10.z); a1[3] = (short)f2bf(p10.w);
    a1[4] = (short)f2bf(p11.x); a1[5] = (short)f2bf(p11.y);
    a1[6] = (short)f2bf(p11.z); a1[7] = (short)f2bf(p11.w);

    #pragma unroll
    for (int nf = 0; nf < 8; ++nf) {
      acc[0][nf] = __builtin_amdgcn_mfma_f32_16x16x32_bf16(a0, b[nf], acc[0][nf], 0, 0, 0);
      acc[1][nf] = __builtin_amdgcn_mfma_f32_16x16x32_bf16(a1, b[nf], acc[1][nf], 0, 0, 0);
    }
  }

  float w1[8], w2[8];
  #pragma unroll
  for (int nf = 0; nf < 8; ++nf) { w1[nf] = a1w[nf * 16 + lr]; w2[nf] = a2w[nf * 16 + lr]; }
  float b1s = a1b[0], b2s = a2b[0];

  #pragma unroll
  for (int mf = 0; mf < 2; ++mf) {
    #pragma unroll
    for (int reg = 0; reg < 4; ++reg) {
      int gr = rowbase + wv * 32 + mf * 16 + lq * 4 + reg;
      float hv[8];
      float p1 = 0.0f, p2 = 0.0f;
      #pragma unroll
      for (int nf = 0; nf < 8; ++nf) {
        hv[nf] = acc[mf][nf][reg];
        p1 += hv[nf] * w1[nf];
        p2 += hv[nf] * w2[nf];
      }
      #pragma unroll
      for (int off = 1; off <= 8; off <<= 1) {
        p1 += __shfl_xor(p1, off);
        p2 += __shfl_xor(p2, off);
      }
      bool rowok = gr < N;
      #pragma unroll
      for (int nf = 0; nf < 8; ++nf) {
        int mine = (int)f2bf(hv[nf]);
        int oth = __shfl_xor(mine, 1);
        if (rowok && !(lr & 1)) {
          unsigned packed = (unsigned)mine | ((unsigned)oth << 16);
          hb[(size_t)gr * 64 + nf * 8 + (lr >> 1)] = packed;
        }
      }
      if (rowok && lr == 0) { f1[gr] = p1 + b1s; f2[gr] = p2 + b2s; }
    }
  }
}

// ---------------- Pass A: LDS radix binning into padded row-buckets ----------------
__global__ __launch_bounds__(256) void binA(const int* __restrict__ row,
                                            const int* __restrict__ col,
                                            const float* __restrict__ w,
                                            const float* __restrict__ f1,
                                            const float* __restrict__ f2,
                                            unsigned* __restrict__ tail,
                                            uint2* __restrict__ stg, int E, int NBKT) {
  __shared__ unsigned bcnt[512];
  __shared__ unsigned bcur[512];
  __shared__ uint2 sstg[PCHUNK];
  const int tid = threadIdx.x;
  const int lane = tid & 63, wv = tid >> 6;
  const int base = blockIdx.x * PCHUNK;

  for (int i = tid; i < 512; i += 256) bcnt[i] = 0u;
  __syncthreads();

  float vv[16];
  unsigned pk[16];
  if (base + PCHUNK <= E) {
    #pragma unroll
    for (int g = 0; g < 4; ++g) {
      int idx = base + g * 1024 + tid * 4;
      int4 r4 = *reinterpret_cast<const int4*>(row + idx);
      int4 c4 = *reinterpret_cast<const int4*>(col + idx);
      float4 w4 = *reinterpret_cast<const float4*>(w + idx);
      int rr[4] = {r4.x, r4.y, r4.z, r4.w};
      int cc[4] = {c4.x, c4.y, c4.z, c4.w};
      float ww[4] = {w4.x, w4.y, w4.z, w4.w};
      #pragma unroll
      for (int i = 0; i < 4; ++i) {
        int l = g * 4 + i;
        float x = f1[rr[i]] + f2[cc[i]];
        x = x > 0.0f ? x : ALPHA * x;
        x *= ww[i];
        vv[l] = x;
        pk[l] = ((unsigned)cc[i] << 16) | (unsigned)rr[i];
        atomicAdd(&bcnt[rr[i] >> 7], 1u);
      }
    }
  } else {
    #pragma unroll
    for (int l = 0; l < 16; ++l) {
      int idx = base + tid + l * 256;
      if (idx < E) {
        int r = row[idx], c = col[idx];
        float x = f1[r] + f2[c];
        x = x > 0.0f ? x : ALPHA * x;
        x *= w[idx];
        vv[l] = x;
        pk[l] = ((unsigned)c << 16) | (unsigned)r;
        atomicAdd(&bcnt[r >> 7], 1u);
      } else {
        pk[l] = 0xFFFFFFFFu;
      }
    }
  }
  __syncthreads();

  unsigned a0 = bcnt[2 * tid], a1 = bcnt[2 * tid + 1];
  unsigned pairv = a0 + a1;
  unsigned x = pairv;
  #pragma unroll
  for (int d = 1; d < 64; d <<= 1) {
    unsigned y = __shfl_up(x, d);
    if (lane >= d) x += y;
  }
  __shared__ unsigned wsum[4];
  if (lane == 63) wsum[wv] = x;
  __syncthreads();
  unsigned woff = 0;
  for (int i = 0; i < wv; ++i) woff += wsum[i];
  unsigned exclp = x + woff - pairv;
  bcur[2 * tid] = exclp;
  bcur[2 * tid + 1] = exclp + a0;
  __syncthreads();

  if (base + PCHUNK <= E) {
    #pragma unroll
    for (int l = 0; l < 16; ++l) {
      unsigned b = (pk[l] & 0xFFFFu) >> 7;
      unsigned p = atomicAdd(&bcur[b], 1u);
      sstg[p] = make_uint2(__float_as_uint(vv[l]), pk[l]);
    }
  } else {
    #pragma unroll
    for (int l = 0; l < 16; ++l) {
      if (pk[l] != 0xFFFFFFFFu) {
        unsigned b = (pk[l] & 0xFFFFu) >> 7;
        unsigned p = atomicAdd(&bcur[b], 1u);
        sstg[p] = make_uint2(__float_as_uint(vv[l]), pk[l]);
      }
    }
  }
  __syncthreads();

  for (int b = tid; b < NBKT; b += 256) {
    unsigned c = bcnt[b];
    if (c) {
      unsigned g = atomicAdd(&tail[b], c);
      bcnt[b] = g - (bcur[b] - c);  // delta = globalstart - ldsstart
    }
  }
  __syncthreads();

  int ne = E - base; if (ne > PCHUNK) ne = PCHUNK;
  for (int i = tid; i < ne; i += 256) {
    uint2 e2 = sstg[i];
    unsigned b = (e2.y & 0xFFFFu) >> 7;
    __builtin_nontemporal_store(e2.x, &stg[i + bcnt[b]].x);
    __builtin_nontemporal_store(e2.y, &stg[i + bcnt[b]].y);
  }
}

// ---------------- Pass B: rowse + softmax + CSR place (eb packed to 4B/edge) ----------------
// eb stores are scattered 4B -> MUST stay cached (NT store here = 91MB HBM
// write-through, measured R33). Regular store only.
__global__ __launch_bounds__(256) void binB(const unsigned* __restrict__ tail,
                                            const uint2* __restrict__ stg,
                                            unsigned* __restrict__ eb,
                                            uint2* __restrict__ rowse,
                                            float* __restrict__ rdArr, int N) {
  const int b = blockIdx.x;
  const int r0 = b * BKT;
  int r1 = r0 + BKT; if (r1 > N) r1 = N;
  const int nrows = r1 - r0;
  __shared__ unsigned cnt[BKT];
  __shared__ unsigned cur[BKT];
  __shared__ unsigned mkey[BKT];
  __shared__ float dsum[BKT];
  const int tid = threadIdx.x;
  if (tid < BKT) { cnt[tid] = 0u; mkey[tid] = 0u; dsum[tid] = 0.0f; }
  __syncthreads();
  const int sA = b * CAP, eA = (int)tail[b];

  for (int i = sA + tid; i < eA; i += 256) {
    uint2 e2 = stg[i];
    unsigned rl = e2.y & 127u;
    atomicAdd(&cnt[rl], 1u);
    atomicMax(&mkey[rl], fkey(__uint_as_float(e2.x)));
  }
  __syncthreads();

  unsigned orig = (tid < BKT) ? cnt[tid] : 0u;
  for (int off = 1; off < BKT; off <<= 1) {
    unsigned v = 0u;
    if (tid < BKT && tid >= off) v = cnt[tid - off];
    __syncthreads();
    if (tid < BKT) cnt[tid] += v;
    __syncthreads();
  }
  if (tid < nrows) {
    unsigned start = (unsigned)sA + cnt[tid] - orig;  // exclusive
    cur[tid] = start;
    rowse[r0 + tid] = make_uint2(start, start + orig);
  }
  __syncthreads();

  for (int i = sA + tid; i < eA; i += 256) {
    uint2 e2 = stg[i];
    unsigned rl = e2.y & 127u;
    unsigned c = e2.y >> 16;
    float ex = __expf(__uint_as_float(e2.x) - kinv(mkey[rl]));
    atomicAdd(&dsum[rl], ex);
    unsigned slot = atomicAdd(&cur[rl], 1u);
    eb[slot] = ((unsigned)f2bf(ex) << 16) | c;
  }
  __syncthreads();

  if (tid < nrows) rdArr[r0 + tid] = 1.0f / fmaxf(dsum[tid], 1e-38f);
}

// ---------------- pull SpMM (gather-only; 4B eb; 16/8-wide tiers + tail) ----------------
__global__ __launch_bounds__(256) void spmm(const uint2* __restrict__ rowse,
                                            const float* __restrict__ rdArr,
                                            const unsigned* __restrict__ eb,
                                            const unsigned* __restrict__ hb,
                                            const float* __restrict__ bias,
                                            float* __restrict__ out, int N) {
  int wid = (blockIdx.x * 256 + threadIdx.x) >> 6;
  int lane = threadIdx.x & 63;
  if (wid >= N) return;
  const uint2 se = rowse[wid];
  const int s = (int)se.x, e = (int)se.y;
  const int qw = lane >> 4;
  const int ql = lane & 15;
  const float rd = rdArr[wid];

  float acc[8] = {};
  int j0 = s + lane;
  float cf_reg = 0.0f;
  int c_reg = 0;
  if (j0 < e) {
    unsigned t = __builtin_nontemporal_load(&eb[j0]);
    cf_reg = bfhi(t) * rd;
    c_reg = (int)(t & 0xFFFFu);
  }
  for (int base = s; base < e; base += 64) {
    if (base != s) {
      int j = base + lane;
      if (j < e) {
        unsigned t = __builtin_nontemporal_load(&eb[j]);
        cf_reg = bfhi(t) * rd;
        c_reg = (int)(t & 0xFFFFu);
      } else {
        cf_reg = 0.0f; c_reg = 0;
      }
    }
    int nloc = e - base; if (nloc > 64) nloc = 64;
    const int full16 = nloc & ~15;
    int bk = 0;
    for (; bk < full16; bk += 16) {
      float cf0 = __shfl(cf_reg, bk + qw);
      int   cc0 = __shfl(c_reg,  bk + qw);
      float cf1 = __shfl(cf_reg, bk + 4 + qw);
      int   cc1 = __shfl(c_reg,  bk + 4 + qw);
      float cf2 = __shfl(cf_reg, bk + 8 + qw);
      int   cc2 = __shfl(c_reg,  bk + 8 + qw);
      float cf3 = __shfl(cf_reg, bk + 12 + qw);
      int   cc3 = __shfl(c_reg,  bk + 12 + qw);
      const uint4 g0 = *reinterpret_cast<const uint4*>(hb + (size_t)cc0 * 64 + ql * 4);
      const uint4 g1 = *reinterpret_cast<const uint4*>(hb + (size_t)cc1 * 64 + ql * 4);
      const uint4 g2 = *reinterpret_cast<const uint4*>(hb + (size_t)cc2 * 64 + ql * 4);
      const uint4 g3 = *reinterpret_cast<const uint4*>(hb + (size_t)cc3 * 64 + ql * 4);
      acc[0] += cf0 * bflo(g0.x); acc[1] += cf0 * bfhi(g0.x);
      acc[2] += cf0 * bflo(g0.y); acc[3] += cf0 * bfhi(g0.y);
      acc[4] += cf0 * bflo(g0.z); acc[5] += cf0 * bfhi(g0.z);
      acc[6] += cf0 * bflo(g0.w); acc[7] += cf0 * bfhi(g0.w);
      acc[0] += cf1 * bflo(g1.x); acc[1] += cf1 * bfhi(g1.x);
      acc[2] += cf1 * bflo(g1.y); acc[3] += cf1 * bfhi(g1.y);
      acc[4] += cf1 * bflo(g1.z); acc[5] += cf1 * bfhi(g1.z);
      acc[6] += cf1 * bflo(g1.w); acc[7] += cf1 * bfhi(g1.w);
      acc[0] += cf2 * bflo(g2.x); acc[1] += cf2 * bfhi(g2.x);
      acc[2] += cf2 * bflo(g2.y); acc[3] += cf2 * bfhi(g2.y);
      acc[4] += cf2 * bflo(g2.z); acc[5] += cf2 * bfhi(g2.z);
      acc[6] += cf2 * bflo(g2.w); acc[7] += cf2 * bfhi(g2.w);
      acc[0] += cf3 * bflo(g3.x); acc[1] += cf3 * bfhi(g3.x);
      acc[2] += cf3 * bflo(g3.y); acc[3] += cf3 * bfhi(g3.y);
      acc[4] += cf3 * bflo(g3.z); acc[5] += cf3 * bfhi(g3.z);
      acc[6] += cf3 * bflo(g3.w); acc[7] += cf3 * bfhi(g3.w);
    }
    const int full8 = nloc & ~7;
    for (; bk < full8; bk += 8) {  // 2 unconditional sub-steps
      float cf0 = __shfl(cf_reg, bk + qw);
      int   cc0 = __shfl(c_reg,  bk + qw);
      float cf1 = __shfl(cf_reg, bk + 4 + qw);
      int   cc1 = __shfl(c_reg,  bk + 4 + qw);
      const uint4 g0 = *reinterpret_cast<const uint4*>(hb + (size_t)cc0 * 64 + ql * 4);
      const uint4 g1 = *reinterpret_cast<const uint4*>(hb + (size_t)cc1 * 64 + ql * 4);
      acc[0] += cf0 * bflo(g0.x); acc[1] += cf0 * bfhi(g0.x);
      acc[2] += cf0 * bflo(g0.y); acc[3] += cf0 * bfhi(g0.y);
      acc[4] += cf0 * bflo(g0.z); acc[5] += cf0 * bfhi(g0.z);
      acc[6] += cf0 * bflo(g0.w); acc[7] += cf0 * bfhi(g0.w);
      acc[0] += cf1 * bflo(g1.x); acc[1] += cf1 * bfhi(g1.x);
      acc[2] += cf1 * bflo(g1.y); acc[3] += cf1 * bfhi(g1.y);
      acc[4] += cf1 * bflo(g1.z); acc[5] += cf1 * bfhi(g1.z);
      acc[6] += cf1 * bflo(g1.w); acc[7] += cf1 * bfhi(g1.w);
    }
    for (; bk < nloc; bk += 4) {  // tail: <=1 predicated sub-step
      int k = bk + qw;
      int ksrc = (k < 64) ? k : 0;
      float cfk = __shfl(cf_reg, ksrc);
      int ck = __shfl(c_reg, ksrc);
      if (k < nloc) {
        const uint4 hv = *reinterpret_cast<const uint4*>(hb + (size_t)ck * 64 + ql * 4);
        acc[0] += cfk * bflo(hv.x); acc[1] += cfk * bfhi(hv.x);
        acc[2] += cfk * bflo(hv.y); acc[3] += cfk * bfhi(hv.y);
        acc[4] += cfk * bflo(hv.z); acc[5] += cfk * bfhi(hv.z);
        acc[6] += cfk * bflo(hv.w); acc[7] += cfk * bfhi(hv.w);
      }
    }
  }

  #pragma unroll
  for (int i = 0; i < 8; ++i) {
    acc[i] += __shfl_xor(acc[i], 16);
    acc[i] += __shfl_xor(acc[i], 32);
  }

  if (qw == 0) {
    const int d0 = ql * 8;
    float4 b0 = *reinterpret_cast<const float4*>(bias + d0);
    float4 b1 = *reinterpret_cast<const float4*>(bias + d0 + 4);
    float* op = out + (size_t)wid * 128 + d0;
    __builtin_nontemporal_store(fmaxf(acc[0] + b0.x, 0.0f), op + 0);
    __builtin_nontemporal_store(fmaxf(acc[1] + b0.y, 0.0f), op + 1);
    __builtin_nontemporal_store(fmaxf(acc[2] + b0.z, 0.0f), op + 2);
    __builtin_nontemporal_store(fmaxf(acc[3] + b0.w, 0.0f), op + 3);
    __builtin_nontemporal_store(fmaxf(acc[4] + b1.x, 0.0f), op + 4);
    __builtin_nontemporal_store(fmaxf(acc[5] + b1.y, 0.0f), op + 5);
    __builtin_nontemporal_store(fmaxf(acc[6] + b1.z, 0.0f), op + 6);
    __builtin_nontemporal_store(fmaxf(acc[7] + b1.w, 0.0f), op + 7);
  }
}

extern "C" void kernel_launch(void* const* d_in, const int* in_sizes, int n_in,
                              void* d_out, int out_size, void* d_ws, size_t ws_size,
                              hipStream_t stream) {
  const float* seq    = (const float*)d_in[0];
  const int*   erow   = (const int*)d_in[1];
  const int*   ecol   = (const int*)d_in[2];
  const float* weight = (const float*)d_in[3];
  const float* W      = (const float*)d_in[4];
  const float* a1w    = (const float*)d_in[5];
  const float* a1b    = (const float*)d_in[6];
  const float* a2w    = (const float*)d_in[7];
  const float* a2b    = (const float*)d_in[8];
  const float* bias   = (const float*)d_in[9];
  const int N = in_sizes[0] / 256;
  const int E = in_sizes[1];
  float* out = (float*)d_out;

  char* p = (char*)d_ws;
  auto alloc = [&](size_t bytes) -> char* {
    char* q = p;
    p += (bytes + 255) & ~(size_t)255;
    return q;
  };
  const int NBKT = (N + BKT - 1) / BKT;
  unsigned* hb       = (unsigned*)alloc((size_t)N * 64 * 4);
  float*    f1       = (float*)alloc((size_t)N * 4);
  float*    f2       = (float*)alloc((size_t)N * 4);
  uint2*    rowse    = (uint2*)alloc((size_t)N * 8);
  float*    rdArr    = (float*)alloc((size_t)N * 4);
  unsigned short* WtG = (unsigned short*)alloc((size_t)128 * 256 * 2);
  unsigned* tail     = (unsigned*)alloc((size_t)NBKT * 4);
  uint2*    stg      = (uint2*)alloc((size_t)NBKT * CAP * 8);
  unsigned* eb       = (unsigned*)alloc((size_t)NBKT * CAP * 4);

  wcvt<<<4, 256, 0, stream>>>(W, WtG, tail, NBKT);
  gemm_fused<<<(N + 127) / 128, 256, 0, stream>>>(seq, WtG, a1w, a1b, a2w, a2b, hb, f1, f2, N);
  binA<<<(E + PCHUNK - 1) / PCHUNK, 256, 0, stream>>>(erow, ecol, weight, f1, f2, tail, stg, E, NBKT);
  binB<<<NBKT, 256, 0, stream>>>(tail, stg, eb, rowse, rdArr, N);
  spmm<<<(N * 64 + 255) / 256, 256, 0, stream>>>(rowse, rdArr, eb, hb, bias, out, N);
}